// Round 1
// baseline (321.784 us; speedup 1.0000x reference)
//
#include <hip/hip_runtime.h>
#include <hip/hip_bf16.h>
#include <cstdint>

// ---------- types ----------
typedef unsigned short us;
typedef us   us8 __attribute__((ext_vector_type(8)));
typedef short s8v __attribute__((ext_vector_type(8)));   // 8 bf16 (4 VGPRs) MFMA A/B frag
typedef float f4v __attribute__((ext_vector_type(4)));   // MFMA C/D frag

// Problem constants (B=4, S=4096, D=1024 fixed by setup_inputs)
#define BB 4
#define SS 4096
#define DD 1024
#define MM (BB * SS)      // 16384
#define NN (2 * DD)       // 2048
#define KK DD             // 1024

// GEMM tiling
#define BM 128
#define BN 128
#define BK 64

// Scan chunking
#define CHUNK 128
#define NC (SS / CHUNK)   // 32

// ---------- fp32 -> bf16 (RNE) ----------
__device__ inline us f2bf(float f) {
  unsigned u = __float_as_uint(f);
  u += 0x7fffu + ((u >> 16) & 1u);
  return (us)(u >> 16);
}

__global__ __launch_bounds__(256) void cvt_bf16(const float* __restrict__ in,
                                                us* __restrict__ out, long n) {
  long i = ((long)blockIdx.x * 256 + threadIdx.x) * 8;
  if (i >= n) return;
  const float4* p = (const float4*)(in + i);
  float4 a = p[0], b = p[1];
  us8 o;
  o[0] = f2bf(a.x); o[1] = f2bf(a.y); o[2] = f2bf(a.z); o[3] = f2bf(a.w);
  o[4] = f2bf(b.x); o[5] = f2bf(b.y); o[6] = f2bf(b.z); o[7] = f2bf(b.w);
  *(us8*)(out + i) = o;
}

// ---------- async global->LDS, 16B per lane ----------
#define GLD16(g, l)                                                        \
  __builtin_amdgcn_global_load_lds(                                        \
      (const __attribute__((address_space(1))) void*)(g),                  \
      (__attribute__((address_space(3))) void*)(l), 16, 0, 0)

// ---------- GEMM: C[M,N] = A[M,K] * B[N,K]^T  (bf16 in, fp32 out) ----------
// m97 structure: 128x128 block tile, 4 waves in 2x2, each wave 4x4 tiles of
// 16x16x32 MFMA. LDS tiles [128][64] bf16 with XOR seg-swizzle:
//   slot(row, s) holds global 16B-segment (s ^ (row&7)) of that row
// so fragment ds_read_b128 across 16 consecutive rows hits distinct banks
// (2-way aliasing only -> free per m136), while global_load_lds's fixed
// base+lane*16 scatter is honored (we permute the per-lane SOURCE address).
__global__ __launch_bounds__(256) void gemm_bt(const us* __restrict__ A,
                                               const us* __restrict__ B,
                                               float* __restrict__ C) {
  __shared__ __align__(16) us As[BM * BK];
  __shared__ __align__(16) us Bs[BN * BK];

  const int tid  = threadIdx.x;
  const int lane = tid & 63;
  const int w    = tid >> 6;      // wave 0..3
  const int wm   = w & 1;         // 2x2 wave grid
  const int wn   = w >> 1;
  const long bm  = (long)blockIdx.x * BM;
  const long bn  = (long)blockIdx.y * BN;

  // staging: each global_load_lds covers 8 rows x 64 cols (1 KiB)
  const int srow = lane >> 3;                 // 0..7 row within 8-row group
  const int sseg = (lane & 7) ^ srow;         // XOR-permuted source segment

  // fragment addressing: A[m = lane&15][k = (lane>>4)*8 + j]
  const int fr = lane & 15;
  const int fq = lane >> 4;                   // 0..3

  int aoff[4][2], boff[4][2];
#pragma unroll
  for (int mt = 0; mt < 4; ++mt) {
    int row = wm * 64 + mt * 16 + fr;
#pragma unroll
    for (int kk = 0; kk < 2; ++kk) {
      int seg = kk * 4 + fq;
      aoff[mt][kk] = row * BK + ((seg ^ (row & 7)) * 8);
    }
  }
#pragma unroll
  for (int nt = 0; nt < 4; ++nt) {
    int row = wn * 64 + nt * 16 + fr;
#pragma unroll
    for (int kk = 0; kk < 2; ++kk) {
      int seg = kk * 4 + fq;
      boff[nt][kk] = row * BK + ((seg ^ (row & 7)) * 8);
    }
  }

  f4v acc[4][4] = {};

  const us* Aw = A + (bm + w * 32 + srow) * (long)KK + sseg * 8;
  const us* Bw = B + (bn + w * 32 + srow) * (long)KK + sseg * 8;

  for (int kt = 0; kt < KK / BK; ++kt) {
    const int k0 = kt * BK;
    __syncthreads();   // previous tile's reads done before overwrite
#pragma unroll
    for (int i = 0; i < 4; ++i) {
      GLD16(Aw + (long)(i * 8) * KK + k0, &As[(w * 32 + i * 8) * BK]);
      GLD16(Bw + (long)(i * 8) * KK + k0, &Bs[(w * 32 + i * 8) * BK]);
    }
    __syncthreads();   // staging visible

#pragma unroll
    for (int kk = 0; kk < 2; ++kk) {
      s8v af[4], bf[4];
#pragma unroll
      for (int mt = 0; mt < 4; ++mt) af[mt] = *(const s8v*)&As[aoff[mt][kk]];
#pragma unroll
      for (int nt = 0; nt < 4; ++nt) bf[nt] = *(const s8v*)&Bs[boff[nt][kk]];
#pragma unroll
      for (int mt = 0; mt < 4; ++mt)
#pragma unroll
        for (int nt = 0; nt < 4; ++nt)
          acc[mt][nt] = __builtin_amdgcn_mfma_f32_16x16x32_bf16(
              af[mt], bf[nt], acc[mt][nt], 0, 0, 0);
    }
  }

  // epilogue: D row = quad*4 + reg, col = lane&15  (m89-verified layout)
#pragma unroll
  for (int mt = 0; mt < 4; ++mt) {
    long rbase = bm + wm * 64 + mt * 16 + fq * 4;
#pragma unroll
    for (int nt = 0; nt < 4; ++nt) {
      long col = bn + wn * 64 + nt * 16 + fr;
      float* cp = C + rbase * NN + col;
#pragma unroll
      for (int r = 0; r < 4; ++r) cp[(long)r * NN] = acc[mt][nt][r];
    }
  }
}

// ---------- gate math (linear-space recurrence; all terms positive) ----------
// h_t = coef*h_{t-1} + v ;  coef = sigmoid(-gate) = 1/(1+e^gate),
// v = sigmoid(gate)*g(hidden), g(x) = x+0.5 (x>=0) else sigmoid(x)
__device__ inline void gate_cv(float hid, float gat, float& coef, float& v) {
  float e = __expf(gat);
  coef = 1.0f / (1.0f + e);
  float z = 1.0f - coef;
  float g = (hid >= 0.0f) ? (hid + 0.5f) : (1.0f / (1.0f + __expf(-hid)));
  v = z * g;
}

// pass1: per (b, d, chunk) compute coeff-product P and chunk-local h (h_in=0)
__global__ __launch_bounds__(256) void scan_pass1(const float* __restrict__ hg,
                                                  float* __restrict__ cp,
                                                  float* __restrict__ ch) {
  const int d = blockIdx.x * 256 + threadIdx.x;   // 0..1023
  const int c = blockIdx.y;
  const int b = blockIdx.z;
  const float* base = hg + ((size_t)b * SS + (size_t)c * CHUNK) * NN;
  float P = 1.0f, h = 0.0f;
  for (int t = 0; t < CHUNK; ++t) {
    float hid = base[(size_t)t * NN + d];
    float gat = base[(size_t)t * NN + d + DD];
    float coef, v;
    gate_cv(hid, gat, coef, v);
    h = fmaf(coef, h, v);
    P *= coef;
  }
  const int idx = c * (BB * DD) + b * DD + d;     // [c][b][d] for coalesced pass2
  cp[idx] = P;
  ch[idx] = h;
}

// pass2: serial scan over the 32 chunk summaries per sequence; 4096 threads
__global__ __launch_bounds__(256) void scan_pass2(const float* __restrict__ cp,
                                                  const float* __restrict__ ch,
                                                  float* __restrict__ carry) {
  const int bd = blockIdx.x * 256 + threadIdx.x;  // 0..4095
  float h = 0.0f;
  for (int c = 0; c < NC; ++c) {
    carry[c * (BB * DD) + bd] = h;                // carry INTO chunk c
    h = fmaf(cp[c * (BB * DD) + bd], h, ch[c * (BB * DD) + bd]);
  }
}

// pass3: re-run each chunk with the correct carry-in, write out = h
__global__ __launch_bounds__(256) void scan_pass3(const float* __restrict__ hg,
                                                  const float* __restrict__ carry,
                                                  float* __restrict__ out) {
  const int d = blockIdx.x * 256 + threadIdx.x;
  const int c = blockIdx.y;
  const int b = blockIdx.z;
  const float* base = hg + ((size_t)b * SS + (size_t)c * CHUNK) * NN;
  float* obase = out + ((size_t)b * SS + (size_t)c * CHUNK) * DD;
  float h = carry[c * (BB * DD) + b * DD + d];
  for (int t = 0; t < CHUNK; ++t) {
    float hid = base[(size_t)t * NN + d];
    float gat = base[(size_t)t * NN + d + DD];
    float coef, v;
    gate_cv(hid, gat, coef, v);
    h = fmaf(coef, h, v);
    obase[(size_t)t * DD + d] = h;
  }
}

// ---------- launch ----------
extern "C" void kernel_launch(void* const* d_in, const int* in_sizes, int n_in,
                              void* d_out, int out_size, void* d_ws, size_t ws_size,
                              hipStream_t stream) {
  const float* x = (const float*)d_in[0];   // [4,4096,1024] fp32
  const float* W = (const float*)d_in[1];   // [2048,1024]  fp32
  float* out = (float*)d_out;               // [4,4096,1024] fp32

  const long nx = (long)MM * KK;            // 16,777,216
  const long nw = (long)NN * KK;            //  2,097,152

  // workspace layout (~166 MiB total)
  char* ws = (char*)d_ws;
  float* hg = (float*)ws;            ws += (size_t)MM * NN * sizeof(float); // 128 MiB
  us* xb = (us*)ws;                  ws += (size_t)nx * sizeof(us);         //  32 MiB
  us* wb = (us*)ws;                  ws += (size_t)nw * sizeof(us);         //   4 MiB
  float* cp = (float*)ws;            ws += (size_t)BB * DD * NC * sizeof(float);
  float* chh = (float*)ws;           ws += (size_t)BB * DD * NC * sizeof(float);
  float* carry = (float*)ws;         ws += (size_t)BB * DD * NC * sizeof(float);

  cvt_bf16<<<(int)(nx / 8 / 256), 256, 0, stream>>>(x, xb, nx);   // 8192 blocks
  cvt_bf16<<<(int)(nw / 8 / 256), 256, 0, stream>>>(W, wb, nw);   // 1024 blocks

  gemm_bt<<<dim3(MM / BM, NN / BN), 256, 0, stream>>>(xb, wb, hg); // 128 x 16

  scan_pass1<<<dim3(DD / 256, NC, BB), 256, 0, stream>>>(hg, cp, chh);
  scan_pass2<<<dim3(BB * DD / 256), 256, 0, stream>>>(cp, chh, carry);
  scan_pass3<<<dim3(DD / 256, NC, BB), 256, 0, stream>>>(hg, carry, out);
}

// Round 2
// 251.458 us; speedup vs baseline: 1.2797x; 1.2797x over previous
//
#include <hip/hip_runtime.h>
#include <hip/hip_bf16.h>
#include <hip/hip_fp16.h>
#include <cstdint>

// ---------- types ----------
typedef unsigned short us;
typedef us   us8 __attribute__((ext_vector_type(8)));
typedef short s8v __attribute__((ext_vector_type(8)));   // 8 bf16 (4 VGPRs) MFMA A/B frag
typedef float f4v __attribute__((ext_vector_type(4)));   // MFMA C/D frag

// Problem constants (B=4, S=4096, D=1024 fixed by setup_inputs)
#define BB 4
#define SS 4096
#define DD 1024
#define MM (BB * SS)      // 16384
#define NN (2 * DD)       // 2048
#define KK DD             // 1024

// GEMM tiling
#define BM 128
#define BN 128
#define BK 64

// Scan chunking (64 chunks x 64 steps -> 1024 blocks in pass1/3)
#define CHUNK 64
#define NC (SS / CHUNK)   // 64

// ---------- fp32 -> bf16 (RNE) ----------
__device__ inline us f2bf(float f) {
  unsigned u = __float_as_uint(f);
  u += 0x7fffu + ((u >> 16) & 1u);
  return (us)(u >> 16);
}

__global__ __launch_bounds__(256) void cvt_bf16(const float* __restrict__ in,
                                                us* __restrict__ out, long n) {
  long i = ((long)blockIdx.x * 256 + threadIdx.x) * 8;
  if (i >= n) return;
  const float4* p = (const float4*)(in + i);
  float4 a = p[0], b = p[1];
  us8 o;
  o[0] = f2bf(a.x); o[1] = f2bf(a.y); o[2] = f2bf(a.z); o[3] = f2bf(a.w);
  o[4] = f2bf(b.x); o[5] = f2bf(b.y); o[6] = f2bf(b.z); o[7] = f2bf(b.w);
  *(us8*)(out + i) = o;
}

// ---------- async global->LDS, 16B per lane ----------
#define GLD16(g, l)                                                        \
  __builtin_amdgcn_global_load_lds(                                        \
      (const __attribute__((address_space(1))) void*)(g),                  \
      (__attribute__((address_space(3))) void*)(l), 16, 0, 0)

// ---------- gate math ----------
// h_t = coef*h_{t-1} + v ;  coef = sigmoid(-gate) = 1/(1+e^gate),
// v = sigmoid(gate)*g(hidden), g(x) = x+0.5 (x>=0) else sigmoid(x)
__device__ inline void gate_cv(float hid, float gat, float& coef, float& v) {
  float e = __expf(gat);
  coef = 1.0f / (1.0f + e);
  float z = 1.0f - coef;
  float g = (hid >= 0.0f) ? (hid + 0.5f) : (1.0f / (1.0f + __expf(-hid)));
  v = z * g;
}

// ---------- fused GEMM + gate epilogue ----------
// C-space: each block covers 64 output channels d in [d0, d0+64).
// B(weight)-tile local row lr (0..127) maps to W row:
//   perm(lr) = d0 + ((lr>>5)<<4) + (lr&15) + (((lr>>4)&1)<<10)
// i.e. col order [hid d0..d0+15 | gate d0..d0+15 | hid d0+16.. | gate ...],
// so wave wn's tile nt=even is hidden, nt=odd is the SAME d's gate, and each
// lane pairs hid/gate at identical (row,d) -> compute coef,v in-register and
// store one half2 per (t,d). LDS XOR seg-swizzle as before (2-way = free).
__global__ __launch_bounds__(256) void gemm_fused(const us* __restrict__ A,
                                                  const us* __restrict__ B,
                                                  __half2* __restrict__ cv) {
  __shared__ __align__(16) us As[BM * BK];
  __shared__ __align__(16) us Bs[BN * BK];

  const int tid  = threadIdx.x;
  const int lane = tid & 63;
  const int w    = tid >> 6;      // wave 0..3
  const int wm   = w & 1;         // 2x2 wave grid
  const int wn   = w >> 1;
  const long bm  = (long)blockIdx.x * BM;
  const int  d0  = blockIdx.y * 64;

  // staging: each global_load_lds covers 8 rows x 64 cols (1 KiB)
  const int srow = lane >> 3;                 // row within 8-row group
  const int sseg = (lane & 7) ^ srow;         // XOR-permuted source segment

  const int fr = lane & 15;
  const int fq = lane >> 4;                   // 0..3

  int aoff[4][2], boff[4][2];
#pragma unroll
  for (int mt = 0; mt < 4; ++mt) {
    int row = wm * 64 + mt * 16 + fr;
#pragma unroll
    for (int kk = 0; kk < 2; ++kk) {
      int seg = kk * 4 + fq;
      aoff[mt][kk] = row * BK + ((seg ^ (row & 7)) * 8);
    }
  }
#pragma unroll
  for (int nt = 0; nt < 4; ++nt) {
    int row = wn * 64 + nt * 16 + fr;
#pragma unroll
    for (int kk = 0; kk < 2; ++kk) {
      int seg = kk * 4 + fq;
      boff[nt][kk] = row * BK + ((seg ^ (row & 7)) * 8);
    }
  }

  f4v acc[4][4] = {};

  const us* Ap[4];
  const us* Bp[4];
#pragma unroll
  for (int i = 0; i < 4; ++i) {
    int lr = w * 32 + i * 8 + srow;           // local tile row
    Ap[i] = A + (bm + lr) * (long)KK + sseg * 8;
    int wrow = d0 + ((lr >> 5) << 4) + (lr & 15) + (((lr >> 4) & 1) << 10);
    Bp[i] = B + (long)wrow * KK + sseg * 8;
  }

  for (int kt = 0; kt < KK / BK; ++kt) {
    const int k0 = kt * BK;
    __syncthreads();   // previous tile's reads done before overwrite
#pragma unroll
    for (int i = 0; i < 4; ++i) {
      GLD16(Ap[i] + k0, &As[(w * 32 + i * 8) * BK]);
      GLD16(Bp[i] + k0, &Bs[(w * 32 + i * 8) * BK]);
    }
    __syncthreads();   // staging visible

#pragma unroll
    for (int kk = 0; kk < 2; ++kk) {
      s8v af[4], bf[4];
#pragma unroll
      for (int mt = 0; mt < 4; ++mt) af[mt] = *(const s8v*)&As[aoff[mt][kk]];
#pragma unroll
      for (int nt = 0; nt < 4; ++nt) bf[nt] = *(const s8v*)&Bs[boff[nt][kk]];
#pragma unroll
      for (int mt = 0; mt < 4; ++mt)
#pragma unroll
        for (int nt = 0; nt < 4; ++nt)
          acc[mt][nt] = __builtin_amdgcn_mfma_f32_16x16x32_bf16(
              af[mt], bf[nt], acc[mt][nt], 0, 0, 0);
    }
  }

  // epilogue: C/D row = fq*4 + r, col = fr (m89 layout); pair (nt=2p, 2p+1)
#pragma unroll
  for (int mt = 0; mt < 4; ++mt) {
    long rb = bm + wm * 64 + mt * 16 + fq * 4;
#pragma unroll
    for (int p = 0; p < 2; ++p) {
      int d = d0 + (wn * 2 + p) * 16 + fr;
      f4v hv = acc[mt][2 * p];
      f4v gv = acc[mt][2 * p + 1];
#pragma unroll
      for (int r = 0; r < 4; ++r) {
        float coef, v;
        gate_cv(hv[r], gv[r], coef, v);
        __half2 o;
        o.x = __float2half_rn(coef);
        o.y = __float2half_rn(v);
        cv[(rb + r) * (size_t)DD + d] = o;
      }
    }
  }
}

// pass1: per (b, d, chunk): coeff-product P and chunk-local h (h_in = 0)
__global__ __launch_bounds__(256) void scan_pass1(const __half2* __restrict__ cv,
                                                  float* __restrict__ cp,
                                                  float* __restrict__ ch) {
  const int d = blockIdx.x * 256 + threadIdx.x;   // 0..1023
  const int c = blockIdx.y;
  const int b = blockIdx.z;
  const __half2* base = cv + ((size_t)b * SS + (size_t)c * CHUNK) * DD + d;
  float P = 1.0f, h = 0.0f;
#pragma unroll 8
  for (int t = 0; t < CHUNK; ++t) {
    __half2 hv = base[(size_t)t * DD];
    float coef = __half2float(hv.x);
    float v    = __half2float(hv.y);
    h = fmaf(coef, h, v);
    P *= coef;
  }
  const int idx = c * (BB * DD) + b * DD + d;     // [c][b][d] coalesced for pass2
  cp[idx] = P;
  ch[idx] = h;
}

// pass2: serial scan over NC chunk summaries per sequence; 4096 threads
__global__ __launch_bounds__(256) void scan_pass2(const float* __restrict__ cp,
                                                  const float* __restrict__ ch,
                                                  float* __restrict__ carry) {
  const int bd = blockIdx.x * 256 + threadIdx.x;  // 0..4095
  float h = 0.0f;
  for (int c = 0; c < NC; ++c) {
    carry[c * (BB * DD) + bd] = h;                // carry INTO chunk c
    h = fmaf(cp[c * (BB * DD) + bd], h, ch[c * (BB * DD) + bd]);
  }
}

// pass3: re-run each chunk with the correct carry-in, write out = h
__global__ __launch_bounds__(256) void scan_pass3(const __half2* __restrict__ cv,
                                                  const float* __restrict__ carry,
                                                  float* __restrict__ out) {
  const int d = blockIdx.x * 256 + threadIdx.x;
  const int c = blockIdx.y;
  const int b = blockIdx.z;
  const __half2* base = cv + ((size_t)b * SS + (size_t)c * CHUNK) * DD + d;
  float* obase = out + ((size_t)b * SS + (size_t)c * CHUNK) * DD + d;
  float h = carry[c * (BB * DD) + b * DD + d];
#pragma unroll 8
  for (int t = 0; t < CHUNK; ++t) {
    __half2 hv = base[(size_t)t * DD];
    h = fmaf(__half2float(hv.x), h, __half2float(hv.y));
    obase[(size_t)t * DD] = h;
  }
}

// ---------- launch ----------
extern "C" void kernel_launch(void* const* d_in, const int* in_sizes, int n_in,
                              void* d_out, int out_size, void* d_ws, size_t ws_size,
                              hipStream_t stream) {
  const float* x = (const float*)d_in[0];   // [4,4096,1024] fp32
  const float* W = (const float*)d_in[1];   // [2048,1024]  fp32
  float* out = (float*)d_out;               // [4,4096,1024] fp32

  const long nx = (long)MM * KK;            // 16,777,216
  const long nw = (long)NN * KK;            //  2,097,152

  // workspace layout (~103 MiB total)
  char* ws = (char*)d_ws;
  __half2* cv = (__half2*)ws;        ws += (size_t)MM * DD * sizeof(__half2); // 64 MiB
  us* xb = (us*)ws;                  ws += (size_t)nx * sizeof(us);           // 32 MiB
  us* wb = (us*)ws;                  ws += (size_t)nw * sizeof(us);           //  4 MiB
  float* cp = (float*)ws;            ws += (size_t)NC * BB * DD * sizeof(float);
  float* chh = (float*)ws;           ws += (size_t)NC * BB * DD * sizeof(float);
  float* carry = (float*)ws;         ws += (size_t)NC * BB * DD * sizeof(float);

  cvt_bf16<<<(int)(nx / 8 / 256), 256, 0, stream>>>(x, xb, nx);   // 8192 blocks
  cvt_bf16<<<(int)(nw / 8 / 256), 256, 0, stream>>>(W, wb, nw);   // 1024 blocks

  gemm_fused<<<dim3(MM / BM, DD / 64), 256, 0, stream>>>(xb, wb, cv); // 128 x 16

  scan_pass1<<<dim3(DD / 256, NC, BB), 256, 0, stream>>>(cv, cp, chh);
  scan_pass2<<<dim3(BB * DD / 256), 256, 0, stream>>>(cp, chh, carry);
  scan_pass3<<<dim3(DD / 256, NC, BB), 256, 0, stream>>>(cv, carry, out);
}